// Round 3
// baseline (583.453 us; speedup 1.0000x reference)
//
#include <hip/hip_runtime.h>

typedef float v2f __attribute__((ext_vector_type(2)));
typedef float v4f __attribute__((ext_vector_type(4)));

#define GRID1 1024
#define ITERS 8   // 1024 blocks * 8 iters * 4 waves * 4 rows = 131072

// DPP controls (row = 16 lanes)
#define DPP_XOR1 0xB1   // quad_perm(1,0,3,2)
#define DPP_XOR2 0x4E   // quad_perm(2,3,0,1)
#define DPP_HMIR 0x141  // row_half_mirror = xor 7
#define DPP_ROR1 0x121
#define DPP_ROR2 0x122
#define DPP_ROR4 0x124
#define DPP_ROR8 0x128

template<int C>
__device__ __forceinline__ float fdpp(float x) {
    return __int_as_float(__builtin_amdgcn_mov_dpp(__float_as_int(x), C, 0xF, 0xF, true));
}
__device__ __forceinline__ float swz16(float x) {  // lane ^= 16 (within 32-lane half)
    return __int_as_float(__builtin_amdgcn_ds_swizzle(__float_as_int(x), 0x401F));
}
__device__ __forceinline__ float bperm(int addr, float x) {  // full-wave pull
    return __int_as_float(__builtin_amdgcn_ds_bpermute(addr, __float_as_int(x)));
}
__device__ __forceinline__ float dot4(v4f a, v4f b) {
    return fmaf(a.x, b.x, fmaf(a.y, b.y, fmaf(a.z, b.z, a.w * b.w)));
}
__device__ __forceinline__ v2f pkfma(v2f a, v2f b, v2f c) {
    return __builtin_elementwise_fma(a, b, c);
}

// LDS: Wp rows tier0 0..63, tier1 64..95, tier2 96..111, stride 68.
// scratch[wave][row][116]: first holds qp (112), then overwritten with
// rbuf = [racc0(64)|racc1(32)|racc2(16)|cw0,cw1,cw2,1.0]. Union is safe:
// all qv reads are hoisted before the first rbuf write (same-wave LDS order).
struct Smem {
    float Wp[112 * 68];        // 30464 B
    float bpb[112];            // 448 B
    float scratch[4][4][116];  // 7424 B  -> total 38336 B => 4 blocks/CU
};

// Tier 0: S=4, dim=64. Lane l holds m[s=l&3][4*(l>>2)..+3].
__device__ __forceinline__ float tier0_proc(int lane, int bp32, v4f m, v4f qv, float* rb) {
    float p = dot4(m, qv);
    p += fdpp<DPP_ROR4>(p);
    p += fdpp<DPP_ROR8>(p);
    p += swz16(p);
    p += bperm(bp32, p);
    float mx = fmaxf(p, fdpp<DPP_XOR1>(p));
    mx = fmaxf(mx, fdpp<DPP_XOR2>(mx));
    float e = __expf(p - mx);
    float den = e + fdpp<DPP_XOR1>(e);
    den += fdpp<DPP_XOR2>(den);
    v4f rv = m * e;
    rv.x += fdpp<DPP_XOR1>(rv.x); rv.y += fdpp<DPP_XOR1>(rv.y);
    rv.z += fdpp<DPP_XOR1>(rv.z); rv.w += fdpp<DPP_XOR1>(rv.w);
    rv.x += fdpp<DPP_XOR2>(rv.x); rv.y += fdpp<DPP_XOR2>(rv.y);
    rv.z += fdpp<DPP_XOR2>(rv.z); rv.w += fdpp<DPP_XOR2>(rv.w);
    if ((lane & 3) == 0) *reinterpret_cast<v4f*>(rb + 4 * (lane >> 2)) = rv;
    return den;
}

// Tier 1: S=8, dim=32. Lane l holds m[s=l&7][4*(l>>3)..+3].
__device__ __forceinline__ float tier1_proc(int lane, int bp32, v4f m, v4f qv, float* rb) {
    float p = dot4(m, qv);
    p += fdpp<DPP_ROR8>(p);
    p += swz16(p);
    p += bperm(bp32, p);
    float mx = fmaxf(p, fdpp<DPP_XOR1>(p));
    mx = fmaxf(mx, fdpp<DPP_XOR2>(mx));
    mx = fmaxf(mx, fdpp<DPP_HMIR>(mx));
    float e = __expf(p - mx);
    float den = e + fdpp<DPP_XOR1>(e);
    den += fdpp<DPP_XOR2>(den);
    den += fdpp<DPP_HMIR>(den);
    v4f rv = m * e;
    rv.x += fdpp<DPP_XOR1>(rv.x); rv.y += fdpp<DPP_XOR1>(rv.y);
    rv.z += fdpp<DPP_XOR1>(rv.z); rv.w += fdpp<DPP_XOR1>(rv.w);
    rv.x += fdpp<DPP_XOR2>(rv.x); rv.y += fdpp<DPP_XOR2>(rv.y);
    rv.z += fdpp<DPP_XOR2>(rv.z); rv.w += fdpp<DPP_XOR2>(rv.w);
    rv.x += fdpp<DPP_HMIR>(rv.x); rv.y += fdpp<DPP_HMIR>(rv.y);
    rv.z += fdpp<DPP_HMIR>(rv.z); rv.w += fdpp<DPP_HMIR>(rv.w);
    if ((lane & 7) == 0) *reinterpret_cast<v4f*>(rb + 4 * (lane >> 3)) = rv;
    return den;
}

// Tier 2: S=16, dim=16. Lane l holds m[s=l&15][4*(l>>4)..+3].
__device__ __forceinline__ float tier2_proc(int lane, int bp32, v4f m, v4f qv, float* rb) {
    float p = dot4(m, qv);
    p += swz16(p);
    p += bperm(bp32, p);
    float mx = fmaxf(p, fdpp<DPP_ROR1>(p));
    mx = fmaxf(mx, fdpp<DPP_ROR2>(mx));
    mx = fmaxf(mx, fdpp<DPP_ROR4>(mx));
    mx = fmaxf(mx, fdpp<DPP_ROR8>(mx));
    float e = __expf(p - mx);
    float den = e + fdpp<DPP_ROR1>(e);
    den += fdpp<DPP_ROR2>(den);
    den += fdpp<DPP_ROR4>(den);
    den += fdpp<DPP_ROR8>(den);
    v4f rv = m * e;
    rv.x += fdpp<DPP_ROR1>(rv.x); rv.y += fdpp<DPP_ROR1>(rv.y);
    rv.z += fdpp<DPP_ROR1>(rv.z); rv.w += fdpp<DPP_ROR1>(rv.w);
    rv.x += fdpp<DPP_ROR2>(rv.x); rv.y += fdpp<DPP_ROR2>(rv.y);
    rv.z += fdpp<DPP_ROR2>(rv.z); rv.w += fdpp<DPP_ROR2>(rv.w);
    rv.x += fdpp<DPP_ROR4>(rv.x); rv.y += fdpp<DPP_ROR4>(rv.y);
    rv.z += fdpp<DPP_ROR4>(rv.z); rv.w += fdpp<DPP_ROR4>(rv.w);
    rv.x += fdpp<DPP_ROR8>(rv.x); rv.y += fdpp<DPP_ROR8>(rv.y);
    rv.z += fdpp<DPP_ROR8>(rv.z); rv.w += fdpp<DPP_ROR8>(rv.w);
    if ((lane & 15) == 0) *reinterpret_cast<v4f*>(rb + 4 * (lane >> 4)) = rv;
    return den;
}

// Prep: waug[o][c] = [Wc@Wu0 | Wc@Wu1 | Wc@Wu2 | Wc@bu0 | Wc@bu1 | Wc@bu2 | bc]
__global__ __launch_bounds__(128) void prep_kernel(
    const float* __restrict__ Wu0, const float* __restrict__ Wu1, const float* __restrict__ Wu2,
    const float* __restrict__ bu0, const float* __restrict__ bu1, const float* __restrict__ bu2,
    const float* __restrict__ Wc,  const float* __restrict__ bc,  float* __restrict__ waug) {
    int o = blockIdx.x;
    int c = threadIdx.x;
    if (c >= 116) return;
    float acc = 0.0f;
    if (c < 112) {
        const float* wu; int d, dim;
        if (c < 64)      { wu = Wu0; d = c;      dim = 64; }
        else if (c < 96) { wu = Wu1; d = c - 64; dim = 32; }
        else             { wu = Wu2; d = c - 96; dim = 16; }
        for (int h = 0; h < 64; ++h) acc = fmaf(Wc[o * 64 + h], wu[h * dim + d], acc);
    } else if (c < 115) {
        const float* bu = (c == 112) ? bu0 : (c == 113) ? bu1 : bu2;
        for (int h = 0; h < 64; ++h) acc = fmaf(Wc[o * 64 + h], bu[h], acc);
    } else {
        acc = bc[o];
    }
    waug[o * 116 + c] = acc;
}

__global__ __launch_bounds__(256, 4) void retrieval_kernel(
    const float* __restrict__ query,
    const float* __restrict__ mem0, const float* __restrict__ mem1, const float* __restrict__ mem2,
    const float* __restrict__ Wp0, const float* __restrict__ bp0,
    const float* __restrict__ Wp1, const float* __restrict__ bp1,
    const float* __restrict__ Wp2, const float* __restrict__ bp2,
    const float* __restrict__ waug, float* __restrict__ out) {
    __shared__ Smem sm;
    const int t = threadIdx.x;
    const int wv = t >> 6;
    const int lane = t & 63;

    // ---- stage Wp (scale 1/sqrt(dim) folded into Wp and bp) ----
    for (int idx = t; idx < 4096; idx += 256) { int r = idx >> 6, k = idx & 63; sm.Wp[r * 68 + k] = Wp0[idx] * 0.125f; }
    for (int idx = t; idx < 2048; idx += 256) { int r = idx >> 6, k = idx & 63; sm.Wp[(64 + r) * 68 + k] = Wp1[idx] * 0.17677669529663687f; }
    for (int idx = t; idx < 1024; idx += 256) { int r = idx >> 6, k = idx & 63; sm.Wp[(96 + r) * 68 + k] = Wp2[idx] * 0.25f; }
    if (t < 112) {
        float sc = (t < 64) ? 0.125f : (t < 96) ? 0.17677669529663687f : 0.25f;
        float v  = (t < 64) ? bp0[t] : (t < 96) ? bp1[t - 64] : bp2[t - 96];
        sm.bpb[t] = v * sc;
    }
    __syncthreads();

    const v4f* w0p = reinterpret_cast<const v4f*>(&sm.Wp[lane * 68]);
    const v4f* w1p = reinterpret_cast<const v4f*>(&sm.Wp[(64 + (lane & 31)) * 68]);
    const v4f* w2p = reinterpret_cast<const v4f*>(&sm.Wp[(96 + (lane & 15)) * 68]);
    const v4f* wgp = reinterpret_cast<const v4f*>(waug + (size_t)lane * 116);
    const float b0 = sm.bpb[lane];
    const float b1 = sm.bpb[64 + (lane & 31)];
    const float b2 = sm.bpb[96 + (lane & 15)];

    const int bp32 = (lane ^ 32) << 2;   // ds_bpermute byte address for xor-32

    // transposed lane->(s, d-quad) mem indices
    const int mi0 = 16 * (lane & 3)  + (lane >> 2);
    const int mi1 = 8  * (lane & 7)  + (lane >> 3);
    const int mi2 = 4  * (lane & 15) + (lane >> 4);

    const int blockRow0 = blockIdx.x * (ITERS * 16);

    for (int it = 0; it < ITERS; ++it) {
        const int r0 = blockRow0 + it * 16 + wv * 4;

        // ---- down-projections with v_pk_fma_f32; q via uniform (scalar) loads ----
        const v4f* qg0 = reinterpret_cast<const v4f*>(query + (size_t)(r0 + 0) * 64);
        const v4f* qg1 = reinterpret_cast<const v4f*>(query + (size_t)(r0 + 1) * 64);
        const v4f* qg2 = reinterpret_cast<const v4f*>(query + (size_t)(r0 + 2) * 64);
        const v4f* qg3 = reinterpret_cast<const v4f*>(query + (size_t)(r0 + 3) * 64);
        v2f acc0[4], acc1[4], acc2[4];
#pragma unroll
        for (int j = 0; j < 4; ++j) { acc0[j] = 0.f; acc1[j] = 0.f; acc2[j] = 0.f; }
#pragma unroll 4
        for (int kb = 0; kb < 16; ++kb) {
            v4f w0 = w0p[kb], w1 = w1p[kb], w2 = w2p[kb];
            v4f q0 = qg0[kb], q1 = qg1[kb], q2 = qg2[kb], q3 = qg3[kb];
            acc0[0] = pkfma(w0.xy, q0.xy, acc0[0]); acc0[0] = pkfma(w0.zw, q0.zw, acc0[0]);
            acc1[0] = pkfma(w1.xy, q0.xy, acc1[0]); acc1[0] = pkfma(w1.zw, q0.zw, acc1[0]);
            acc2[0] = pkfma(w2.xy, q0.xy, acc2[0]); acc2[0] = pkfma(w2.zw, q0.zw, acc2[0]);
            acc0[1] = pkfma(w0.xy, q1.xy, acc0[1]); acc0[1] = pkfma(w0.zw, q1.zw, acc0[1]);
            acc1[1] = pkfma(w1.xy, q1.xy, acc1[1]); acc1[1] = pkfma(w1.zw, q1.zw, acc1[1]);
            acc2[1] = pkfma(w2.xy, q1.xy, acc2[1]); acc2[1] = pkfma(w2.zw, q1.zw, acc2[1]);
            acc0[2] = pkfma(w0.xy, q2.xy, acc0[2]); acc0[2] = pkfma(w0.zw, q2.zw, acc0[2]);
            acc1[2] = pkfma(w1.xy, q2.xy, acc1[2]); acc1[2] = pkfma(w1.zw, q2.zw, acc1[2]);
            acc2[2] = pkfma(w2.xy, q2.xy, acc2[2]); acc2[2] = pkfma(w2.zw, q2.zw, acc2[2]);
            acc0[3] = pkfma(w0.xy, q3.xy, acc0[3]); acc0[3] = pkfma(w0.zw, q3.zw, acc0[3]);
            acc1[3] = pkfma(w1.xy, q3.xy, acc1[3]); acc1[3] = pkfma(w1.zw, q3.zw, acc1[3]);
            acc2[3] = pkfma(w2.xy, q3.xy, acc2[3]); acc2[3] = pkfma(w2.zw, q3.zw, acc2[3]);
        }
#pragma unroll
        for (int j = 0; j < 4; ++j) {
            float* sc = &sm.scratch[wv][j][0];
            sc[lane] = acc0[j].x + acc0[j].y + b0;
            if (lane < 32) sc[64 + lane] = acc1[j].x + acc1[j].y + b1;
            if (lane < 16) sc[96 + lane] = acc2[j].x + acc2[j].y + b2;
        }

        // ---- per-row tiers; mem tiles prefetched with 1-row lookahead ----
        v4f mcur[3];
        mcur[0] = reinterpret_cast<const v4f*>(mem0 + (size_t)r0 * 256)[mi0];
        mcur[1] = reinterpret_cast<const v4f*>(mem1 + (size_t)r0 * 256)[mi1];
        mcur[2] = reinterpret_cast<const v4f*>(mem2 + (size_t)r0 * 256)[mi2];
        float cf0[4], cf1[4], cf2[4];
#pragma unroll
        for (int j = 0; j < 4; ++j) {
            v4f mnext[3];
            if (j < 3) {
                mnext[0] = reinterpret_cast<const v4f*>(mem0 + (size_t)(r0 + j + 1) * 256)[mi0];
                mnext[1] = reinterpret_cast<const v4f*>(mem1 + (size_t)(r0 + j + 1) * 256)[mi1];
                mnext[2] = reinterpret_cast<const v4f*>(mem2 + (size_t)(r0 + j + 1) * 256)[mi2];
            }
            float* sc = &sm.scratch[wv][j][0];
            // hoist ALL qp reads before the first rbuf write (union safety)
            v4f qv0 = *reinterpret_cast<const v4f*>(sc + 4 * (lane >> 2));
            v4f qv1 = *reinterpret_cast<const v4f*>(sc + 64 + 4 * (lane >> 3));
            v4f qv2 = *reinterpret_cast<const v4f*>(sc + 96 + 4 * (lane >> 4));
            float den0 = tier0_proc(lane, bp32, mcur[0], qv0, sc);
            float den1 = tier1_proc(lane, bp32, mcur[1], qv1, sc + 64);
            float den2 = tier2_proc(lane, bp32, mcur[2], qv2, sc + 96);
            float c0 = __frcp_rn(den0), c1 = __frcp_rn(den1), c2 = __frcp_rn(den2);
            float cm = fmaxf(c0, fmaxf(c1, c2));
            float e0 = __expf(c0 - cm), e1 = __expf(c1 - cm), e2 = __expf(c2 - cm);
            float ics = __frcp_rn(e0 + e1 + e2);
            float cw0 = e0 * ics, cw1 = e1 * ics, cw2 = e2 * ics;
            cf0[j] = cw0 * c0;
            cf1[j] = cw1 * c1;
            cf2[j] = cw2 * c2;
            float ext = (lane == 0) ? cw0 : (lane == 1) ? cw1 : (lane == 2) ? cw2 : 1.0f;
            if (lane < 4) sc[112 + lane] = ext;
            mcur[0] = mnext[0]; mcur[1] = mnext[1]; mcur[2] = mnext[2];
        }

        // ---- fused epilogue: 116-col dot vs waug row `lane` (global, L1/L2-hot) ----
        v2f t0a[4] = {{0,0},{0,0},{0,0},{0,0}};
        v2f t1a[4] = {{0,0},{0,0},{0,0},{0,0}};
        v2f t2a[4] = {{0,0},{0,0},{0,0},{0,0}};
        float t3[4];
#pragma unroll 4
        for (int cb = 0; cb < 16; ++cb) {
            v4f w = wgp[cb];
#pragma unroll
            for (int j = 0; j < 4; ++j) {
                v4f rv = reinterpret_cast<const v4f*>(&sm.scratch[wv][j][0])[cb];
                t0a[j] = pkfma(w.xy, rv.xy, t0a[j]); t0a[j] = pkfma(w.zw, rv.zw, t0a[j]);
            }
        }
#pragma unroll 4
        for (int cb = 16; cb < 24; ++cb) {
            v4f w = wgp[cb];
#pragma unroll
            for (int j = 0; j < 4; ++j) {
                v4f rv = reinterpret_cast<const v4f*>(&sm.scratch[wv][j][0])[cb];
                t1a[j] = pkfma(w.xy, rv.xy, t1a[j]); t1a[j] = pkfma(w.zw, rv.zw, t1a[j]);
            }
        }
#pragma unroll
        for (int cb = 24; cb < 28; ++cb) {
            v4f w = wgp[cb];
#pragma unroll
            for (int j = 0; j < 4; ++j) {
                v4f rv = reinterpret_cast<const v4f*>(&sm.scratch[wv][j][0])[cb];
                t2a[j] = pkfma(w.xy, rv.xy, t2a[j]); t2a[j] = pkfma(w.zw, rv.zw, t2a[j]);
            }
        }
        {
            v4f w = wgp[28];
#pragma unroll
            for (int j = 0; j < 4; ++j) {
                v4f rv = reinterpret_cast<const v4f*>(&sm.scratch[wv][j][0])[28];
                t3[j] = dot4(w, rv);
            }
        }
#pragma unroll
        for (int j = 0; j < 4; ++j) {
            float r = fmaf(cf0[j], t0a[j].x + t0a[j].y,
                      fmaf(cf1[j], t1a[j].x + t1a[j].y,
                      fmaf(cf2[j], t2a[j].x + t2a[j].y, t3[j])));
            out[(size_t)(r0 + j) * 64 + lane] = r;
        }
    }
}

extern "C" void kernel_launch(void* const* d_in, const int* in_sizes, int n_in,
                              void* d_out, int out_size, void* d_ws, size_t ws_size,
                              hipStream_t stream) {
    const float* query = (const float*)d_in[0];
    const float* mem0  = (const float*)d_in[1];
    const float* mem1  = (const float*)d_in[2];
    const float* mem2  = (const float*)d_in[3];
    const float* Wp0   = (const float*)d_in[4];
    const float* bp0   = (const float*)d_in[5];
    const float* Wu0   = (const float*)d_in[6];
    const float* bu0   = (const float*)d_in[7];
    const float* Wp1   = (const float*)d_in[8];
    const float* bp1   = (const float*)d_in[9];
    const float* Wu1   = (const float*)d_in[10];
    const float* bu1   = (const float*)d_in[11];
    const float* Wp2   = (const float*)d_in[12];
    const float* bp2   = (const float*)d_in[13];
    const float* Wu2   = (const float*)d_in[14];
    const float* bu2   = (const float*)d_in[15];
    const float* Wc    = (const float*)d_in[16];
    const float* bc    = (const float*)d_in[17];
    float* waug = (float*)d_ws;   // 64*116 floats = 29696 B
    float* outp = (float*)d_out;

    prep_kernel<<<64, 128, 0, stream>>>(Wu0, Wu1, Wu2, bu0, bu1, bu2, Wc, bc, waug);
    retrieval_kernel<<<GRID1, 256, 0, stream>>>(query, mem0, mem1, mem2,
                                                Wp0, bp0, Wp1, bp1, Wp2, bp2,
                                                waug, outp);
}